// Round 1
// baseline (85.927 us; speedup 1.0000x reference)
//
#include <hip/hip_runtime.h>

namespace {
constexpr int DIM = 16;       // 2^4 qubits
constexpr int BATCH = 8;
constexpr int H = 96, W = 96, CH = 16;
constexpr int OH = 95, OW = 95;
constexpr int NF = 8, NW = 24;
constexpr int NPIX = BATCH * OH * OW;  // 72200
}

__global__ __launch_bounds__(256)
void qconv_kernel(const float* __restrict__ x, const float* __restrict__ wts,
                  float* __restrict__ out) {
  __shared__ float lc[NF * NW];
  __shared__ float ls[NF * NW];
  const int tid = threadIdx.x;
  if (tid < NF * NW) {
    const float h = wts[tid] * 0.5f;
    float s, c;
    __sincosf(h, &s, &c);
    lc[tid] = c;
    ls[tid] = s;
  }
  __syncthreads();

  const int n = blockIdx.x * 256 + tid;
  if (n >= NPIX) return;
  const int b = n / (OH * OW);
  const int rem = n - b * (OH * OW);
  const int oi = rem / OW;
  const int oj = rem - oi * OW;

  // --- patch load: 2 rows x 32 contiguous floats (8 float4 each), 64B aligned ---
  const float* base = x + (((b * H) + oi) * W + oj) * CH;
  float sumsq = 0.f;
  float4 f0 = make_float4(0.f, 0.f, 0.f, 0.f);
#pragma unroll
  for (int fi = 0; fi < 2; ++fi) {
    const float4* row = reinterpret_cast<const float4*>(base + fi * W * CH);
#pragma unroll
    for (int k = 0; k < 8; ++k) {
      const float4 v = row[k];
      if (fi == 0 && k == 0) f0 = v;
      sumsq = fmaf(v.x, v.x, sumsq);
      sumsq = fmaf(v.y, v.y, sumsq);
      sumsq = fmaf(v.z, v.z, sumsq);
      sumsq = fmaf(v.w, v.w, sumsq);
    }
  }
  const float inv = rsqrtf(fmaxf(sumsq, 1e-12f));

  // --- initial product state after RY(ang_q) on |0> ---
  float cq[4], sq[4];
  __sincosf(f0.x * inv * 0.5f, &sq[0], &cq[0]);
  __sincosf(f0.y * inv * 0.5f, &sq[1], &cq[1]);
  __sincosf(f0.z * inv * 0.5f, &sq[2], &cq[2]);
  __sincosf(f0.w * inv * 0.5f, &sq[3], &cq[3]);

  float init[DIM];
#pragma unroll
  for (int i = 0; i < DIM; ++i) {
    init[i] = ((i & 8) ? sq[0] : cq[0]) * ((i & 4) ? sq[1] : cq[1]) *
              ((i & 2) ? sq[2] : cq[2]) * ((i & 1) ? sq[3] : cq[3]);
  }
  // CNOT chain (0,1),(1,2),(2,3); qubit q -> bit (3-q) of index
#pragma unroll
  for (int i = 0; i < DIM; ++i)
    if ((i & 8) && !(i & 4)) { const float t = init[i]; init[i] = init[i | 4]; init[i | 4] = t; }
#pragma unroll
  for (int i = 0; i < DIM; ++i)
    if ((i & 4) && !(i & 2)) { const float t = init[i]; init[i] = init[i | 2]; init[i | 2] = t; }
#pragma unroll
  for (int i = 0; i < DIM; ++i)
    if ((i & 2) && !(i & 1)) { const float t = init[i]; init[i] = init[i | 1]; init[i | 1] = t; }

  float* op = out + n * NF;
  for (int f = 0; f < NF; ++f) {
    const float* fc = lc + f * NW;
    const float* fs = ls + f * NW;
    float ar[DIM], ai[DIM];
#pragma unroll
    for (int i = 0; i < DIM; ++i) { ar[i] = init[i]; ai[i] = 0.f; }

#pragma unroll
    for (int layer = 0; layer < 2; ++layer) {
      const int wb = layer * 12;
#pragma unroll
      for (int q = 0; q < 4; ++q) {
        const int m = 8 >> q;
        {  // RX: [[c,-is],[-is,c]]
          const float c = fc[wb + q * 3], s = fs[wb + q * 3];
#pragma unroll
          for (int i = 0; i < DIM; ++i) {
            if (i & m) continue;
            const int j = i | m;
            const float a0r = ar[i], a0i = ai[i], a1r = ar[j], a1i = ai[j];
            ar[i] = fmaf(c, a0r,  s * a1i);
            ai[i] = fmaf(c, a0i, -s * a1r);
            ar[j] = fmaf(c, a1r,  s * a0i);
            ai[j] = fmaf(c, a1i, -s * a0r);
          }
        }
        {  // RY: [[c,-s],[s,c]]
          const float c = fc[wb + q * 3 + 1], s = fs[wb + q * 3 + 1];
#pragma unroll
          for (int i = 0; i < DIM; ++i) {
            if (i & m) continue;
            const int j = i | m;
            const float a0r = ar[i], a0i = ai[i], a1r = ar[j], a1i = ai[j];
            ar[i] = fmaf(c, a0r, -s * a1r);
            ai[i] = fmaf(c, a0i, -s * a1i);
            ar[j] = fmaf(s, a0r,  c * a1r);
            ai[j] = fmaf(s, a0i,  c * a1i);
          }
        }
        {  // RZ: diag(c-is, c+is)
          const float c = fc[wb + q * 3 + 2], s = fs[wb + q * 3 + 2];
#pragma unroll
          for (int i = 0; i < DIM; ++i) {
            const float r = ar[i], im = ai[i];
            if (i & m) {
              ar[i] = fmaf(c, r, -s * im);
              ai[i] = fmaf(c, im,  s * r);
            } else {
              ar[i] = fmaf(c, r,   s * im);
              ai[i] = fmaf(c, im, -s * r);
            }
          }
        }
      }
      {  // CRY(w[wb+0], ctrl=q0 bit8, tgt=q1 bit4)
        const float c = fc[wb + 0], s = fs[wb + 0];
#pragma unroll
        for (int i = 0; i < DIM; ++i) {
          if (!(i & 8) || (i & 4)) continue;
          const int j = i | 4;
          const float a0r = ar[i], a0i = ai[i], a1r = ar[j], a1i = ai[j];
          ar[i] = fmaf(c, a0r, -s * a1r);
          ai[i] = fmaf(c, a0i, -s * a1i);
          ar[j] = fmaf(s, a0r,  c * a1r);
          ai[j] = fmaf(s, a0i,  c * a1i);
        }
      }
      {  // CRY(w[wb+2], ctrl=q2 bit2, tgt=q3 bit1)
        const float c = fc[wb + 2], s = fs[wb + 2];
#pragma unroll
        for (int i = 0; i < DIM; ++i) {
          if (!(i & 2) || (i & 1)) continue;
          const int j = i | 1;
          const float a0r = ar[i], a0i = ai[i], a1r = ar[j], a1i = ai[j];
          ar[i] = fmaf(c, a0r, -s * a1r);
          ai[i] = fmaf(c, a0i, -s * a1i);
          ar[j] = fmaf(s, a0r,  c * a1r);
          ai[j] = fmaf(s, a0i,  c * a1i);
        }
      }
    }

    // expectation vs Z_MEAN: only popcount 0,1,3,4 indices contribute
    float p[DIM];
#pragma unroll
    for (int i = 0; i < DIM; ++i) p[i] = fmaf(ar[i], ar[i], ai[i] * ai[i]);
    const float acc = (p[0] - p[15]) +
                      0.5f * ((p[1] + p[2] + p[4] + p[8]) -
                              (p[7] + p[11] + p[13] + p[14]));
    op[f] = acc;
  }
}

extern "C" void kernel_launch(void* const* d_in, const int* in_sizes, int n_in,
                              void* d_out, int out_size, void* d_ws, size_t ws_size,
                              hipStream_t stream) {
  const float* x = (const float*)d_in[0];
  const float* w = (const float*)d_in[1];
  float* out = (float*)d_out;
  const int nblocks = (NPIX + 255) / 256;
  qconv_kernel<<<dim3(nblocks), dim3(256), 0, stream>>>(x, w, out);
}

// Round 2
// 76.970 us; speedup vs baseline: 1.1164x; 1.1164x over previous
//
#include <hip/hip_runtime.h>

namespace {
constexpr int DIM = 16;       // 2^4 qubits
constexpr int BATCH = 8;
constexpr int H = 96, W = 96, CH = 16;
constexpr int OH = 95, OW = 95;
constexpr int NF = 8, NW = 24;
constexpr int NPIX = BATCH * OH * OW;        // 72200
constexpr int NTHREAD = NPIX * NF;           // 577600
}

__global__ __launch_bounds__(256)
void qconv_kernel(const float* __restrict__ x, const float* __restrict__ wts,
                  float* __restrict__ out) {
  // trig LUT, transposed layout [k][f] so 8 filter-lanes hit 8 consecutive words
  __shared__ float lc[NW * NF];
  __shared__ float ls[NW * NF];
  const int tid = threadIdx.x;
  if (tid < NF * NW) {
    const int f = tid / NW;
    const int k = tid - f * NW;
    const float h = wts[tid] * 0.5f;
    float s, c;
    __sincosf(h, &s, &c);
    lc[k * NF + f] = c;
    ls[k * NF + f] = s;
  }
  __syncthreads();

  const int t = blockIdx.x * 256 + tid;
  const int n = t >> 3;      // patch index
  const int f = t & 7;       // filter index (also lane-in-patch-group)
  if (n >= NPIX) return;

  const int b = n / (OH * OW);
  const int rem = n - b * (OH * OW);
  const int oi = rem / OW;
  const int oj = rem - oi * OW;

  // --- cooperative patch sum-of-squares: each of 8 lanes loads 8 floats ---
  const float* base = x + (((b * H) + oi) * W + oj) * CH;
  const float4* lp = reinterpret_cast<const float4*>(
      base + (f >> 2) * W * CH + (f & 3) * 8);
  const float4 v0 = lp[0];
  const float4 v1 = lp[1];
  float ss = 0.f;
  ss = fmaf(v0.x, v0.x, ss); ss = fmaf(v0.y, v0.y, ss);
  ss = fmaf(v0.z, v0.z, ss); ss = fmaf(v0.w, v0.w, ss);
  ss = fmaf(v1.x, v1.x, ss); ss = fmaf(v1.y, v1.y, ss);
  ss = fmaf(v1.z, v1.z, ss); ss = fmaf(v1.w, v1.w, ss);
  ss += __shfl_xor(ss, 1);
  ss += __shfl_xor(ss, 2);
  ss += __shfl_xor(ss, 4);
  const float inv = rsqrtf(fmaxf(ss, 1e-12f));

  // first 4 channels of pixel (oi,oj): L1-hot reload
  const float4 f0 = *reinterpret_cast<const float4*>(base);

  // --- initial product state after RY(ang_q) on |0> ---
  float cq[4], sq[4];
  __sincosf(f0.x * inv * 0.5f, &sq[0], &cq[0]);
  __sincosf(f0.y * inv * 0.5f, &sq[1], &cq[1]);
  __sincosf(f0.z * inv * 0.5f, &sq[2], &cq[2]);
  __sincosf(f0.w * inv * 0.5f, &sq[3], &cq[3]);

  float ar[DIM], ai[DIM];
#pragma unroll
  for (int i = 0; i < DIM; ++i) {
    ar[i] = ((i & 8) ? sq[0] : cq[0]) * ((i & 4) ? sq[1] : cq[1]) *
            ((i & 2) ? sq[2] : cq[2]) * ((i & 1) ? sq[3] : cq[3]);
    ai[i] = 0.f;
  }
  // CNOT chain (0,1),(1,2),(2,3); qubit q -> bit (3-q) of index
#pragma unroll
  for (int i = 0; i < DIM; ++i)
    if ((i & 8) && !(i & 4)) { const float tt = ar[i]; ar[i] = ar[i | 4]; ar[i | 4] = tt; }
#pragma unroll
  for (int i = 0; i < DIM; ++i)
    if ((i & 4) && !(i & 2)) { const float tt = ar[i]; ar[i] = ar[i | 2]; ar[i | 2] = tt; }
#pragma unroll
  for (int i = 0; i < DIM; ++i)
    if ((i & 2) && !(i & 1)) { const float tt = ar[i]; ar[i] = ar[i | 1]; ar[i | 1] = tt; }

#define FC(k) lc[(k) * NF + f]
#define FS_(k) ls[(k) * NF + f]

#pragma unroll
  for (int layer = 0; layer < 2; ++layer) {
    const int wb = layer * 12;
#pragma unroll
    for (int q = 0; q < 4; ++q) {
      const int m = 8 >> q;
      {  // RX: [[c,-is],[-is,c]]
        const float c = FC(wb + q * 3), s = FS_(wb + q * 3);
#pragma unroll
        for (int i = 0; i < DIM; ++i) {
          if (i & m) continue;
          const int j = i | m;
          const float a0r = ar[i], a0i = ai[i], a1r = ar[j], a1i = ai[j];
          ar[i] = fmaf(c, a0r,  s * a1i);
          ai[i] = fmaf(c, a0i, -s * a1r);
          ar[j] = fmaf(c, a1r,  s * a0i);
          ai[j] = fmaf(c, a1i, -s * a0r);
        }
      }
      {  // RY: [[c,-s],[s,c]]
        const float c = FC(wb + q * 3 + 1), s = FS_(wb + q * 3 + 1);
#pragma unroll
        for (int i = 0; i < DIM; ++i) {
          if (i & m) continue;
          const int j = i | m;
          const float a0r = ar[i], a0i = ai[i], a1r = ar[j], a1i = ai[j];
          ar[i] = fmaf(c, a0r, -s * a1r);
          ai[i] = fmaf(c, a0i, -s * a1i);
          ar[j] = fmaf(s, a0r,  c * a1r);
          ai[j] = fmaf(s, a0i,  c * a1i);
        }
      }
      {  // RZ: diag(c-is, c+is)
        const float c = FC(wb + q * 3 + 2), s = FS_(wb + q * 3 + 2);
#pragma unroll
        for (int i = 0; i < DIM; ++i) {
          const float r = ar[i], im = ai[i];
          if (i & m) {
            ar[i] = fmaf(c, r, -s * im);
            ai[i] = fmaf(c, im,  s * r);
          } else {
            ar[i] = fmaf(c, r,   s * im);
            ai[i] = fmaf(c, im, -s * r);
          }
        }
      }
    }
    {  // CRY(w[wb+0], ctrl=q0 bit8, tgt=q1 bit4)
      const float c = FC(wb + 0), s = FS_(wb + 0);
#pragma unroll
      for (int i = 0; i < DIM; ++i) {
        if (!(i & 8) || (i & 4)) continue;
        const int j = i | 4;
        const float a0r = ar[i], a0i = ai[i], a1r = ar[j], a1i = ai[j];
        ar[i] = fmaf(c, a0r, -s * a1r);
        ai[i] = fmaf(c, a0i, -s * a1i);
        ar[j] = fmaf(s, a0r,  c * a1r);
        ai[j] = fmaf(s, a0i,  c * a1i);
      }
    }
    {  // CRY(w[wb+2], ctrl=q2 bit2, tgt=q3 bit1)
      const float c = FC(wb + 2), s = FS_(wb + 2);
#pragma unroll
      for (int i = 0; i < DIM; ++i) {
        if (!(i & 2) || (i & 1)) continue;
        const int j = i | 1;
        const float a0r = ar[i], a0i = ai[i], a1r = ar[j], a1i = ai[j];
        ar[i] = fmaf(c, a0r, -s * a1r);
        ai[i] = fmaf(c, a0i, -s * a1i);
        ar[j] = fmaf(s, a0r,  c * a1r);
        ai[j] = fmaf(s, a0i,  c * a1i);
      }
    }
  }
#undef FC
#undef FS_

  // expectation vs Z_MEAN: Z_MEAN[i] = 1 - popcount(i)/2
  float p[DIM];
#pragma unroll
  for (int i = 0; i < DIM; ++i) p[i] = fmaf(ar[i], ar[i], ai[i] * ai[i]);
  const float acc = (p[0] - p[15]) +
                    0.5f * ((p[1] + p[2] + p[4] + p[8]) -
                            (p[7] + p[11] + p[13] + p[14]));
  out[t] = acc;
}

extern "C" void kernel_launch(void* const* d_in, const int* in_sizes, int n_in,
                              void* d_out, int out_size, void* d_ws, size_t ws_size,
                              hipStream_t stream) {
  const float* x = (const float*)d_in[0];
  const float* w = (const float*)d_in[1];
  float* out = (float*)d_out;
  const int nblocks = (NTHREAD + 255) / 256;
  qconv_kernel<<<dim3(nblocks), dim3(256), 0, stream>>>(x, w, out);
}